// Round 1
// baseline (290.721 us; speedup 1.0000x reference)
//
#include <hip/hip_runtime.h>
#include <cstdint>

#define N_NODES 10000
#define N_EDGES 320000
#define DIN 512
#define DOUT 256

using short8 = __attribute__((ext_vector_type(8))) short;
using f32x4  = __attribute__((ext_vector_type(4))) float;

static __device__ __forceinline__ unsigned short f2bf(float f) {
  unsigned u = __builtin_bit_cast(unsigned, f);
  u += 0x7fffu + ((u >> 16) & 1u);   // round-to-nearest-even
  return (unsigned short)(u >> 16);
}
static __device__ __forceinline__ float bf2f(unsigned short s) {
  unsigned u = ((unsigned)s) << 16;
  return __builtin_bit_cast(float, u);
}

// edge_index may be int64 (reference dtype) or int32 (harness convention).
// flag==1 -> int64 layout (low word at 2*i), flag==0 -> int32.
static __device__ __forceinline__ int load_idx(const unsigned* ei, int i, int is64) {
  return is64 ? (int)ei[2 * i] : (int)ei[i];
}

__global__ void detect_k(const unsigned* __restrict__ ei, int* __restrict__ flag) {
  if (threadIdx.x == 0 && blockIdx.x == 0) {
    unsigned z = 0;
    for (int i = 1; i < 32; i += 2) z |= ei[i];   // high words if int64
    *flag = (z == 0u) ? 1 : 0;
  }
}

__global__ void degree_k(const unsigned* __restrict__ ei, const int* __restrict__ flag,
                         int* __restrict__ deg) {
  int e = blockIdx.x * blockDim.x + threadIdx.x;
  if (e >= N_EDGES) return;
  int is64 = *flag;
  int d = load_idx(ei, N_EDGES + e, is64);
  atomicAdd(&deg[d], 1);
}

// single-block exclusive scan over deg -> row_ptr (+ cursor copy). 1024 thr, 10 elems each.
__global__ __launch_bounds__(1024) void scan_k(const int* __restrict__ deg,
                                               int* __restrict__ rowp,
                                               int* __restrict__ cursor) {
  __shared__ int buf[1024];
  int tid = threadIdx.x;
  int loc[10];
  int s = 0;
  #pragma unroll
  for (int q = 0; q < 10; ++q) {
    int i = tid * 10 + q;
    int v = (i < N_NODES) ? deg[i] : 0;
    loc[q] = s;            // local exclusive prefix
    s += v;
  }
  buf[tid] = s;
  __syncthreads();
  #pragma unroll
  for (int off = 1; off < 1024; off <<= 1) {
    int t = (tid >= off) ? buf[tid - off] : 0;
    __syncthreads();
    buf[tid] += t;
    __syncthreads();
  }
  int excl = buf[tid] - s;   // exclusive prefix of this thread's chunk
  #pragma unroll
  for (int q = 0; q < 10; ++q) {
    int i = tid * 10 + q;
    if (i < N_NODES) {
      int val = excl + loc[q];
      rowp[i] = val;
      cursor[i] = val;
    }
  }
  if (tid == 1023) rowp[N_NODES] = buf[1023];   // == E
}

__global__ void scatter_k(const unsigned* __restrict__ ei, const int* __restrict__ flag,
                          int* __restrict__ cursor, int* __restrict__ srcs) {
  int e = blockIdx.x * blockDim.x + threadIdx.x;
  if (e >= N_EDGES) return;
  int is64 = *flag;
  int d = load_idx(ei, N_EDGES + e, is64);
  int s = load_idx(ei, e, is64);
  int pos = atomicAdd(&cursor[d], 1);
  srcs[pos] = s;
}

// Pack/transpose weights to bf16, k-contiguous: W0T[n][k]=W0[k][n];
// WT1[n][k] = (k<256 ? Wl1[k][n] : Wr1[k-256][n]); same for WT2.
__global__ void prep_w(const float* __restrict__ W0,
                       const float* __restrict__ Wl1, const float* __restrict__ Wr1,
                       const float* __restrict__ Wl2, const float* __restrict__ Wr2,
                       unsigned short* __restrict__ W0T, unsigned short* __restrict__ WT1,
                       unsigned short* __restrict__ WT2) {
  int g = blockIdx.x * blockDim.x + threadIdx.x;
  if (g >= 3 * 256 * 512) return;
  int mat = g >> 17;
  int r = g & (131072 - 1);
  int n = r >> 9, k = r & 511;
  float v;
  unsigned short* dst;
  if (mat == 0)      { v = W0[k * 256 + n]; dst = W0T; }
  else if (mat == 1) { v = (k < 256) ? Wl1[k * 256 + n] : Wr1[(k - 256) * 256 + n]; dst = WT1; }
  else               { v = (k < 256) ? Wl2[k * 256 + n] : Wr2[(k - 256) * 256 + n]; dst = WT2; }
  dst[r] = f2bf(v);
}

// CSR mean-aggregate: one wave per node, lane covers 4 cols (uint2 = 4 bf16).
__global__ __launch_bounds__(256) void agg_mean(const unsigned short* __restrict__ h,
                                                const int* __restrict__ rowp,
                                                const int* __restrict__ srcs,
                                                const int* __restrict__ deg,
                                                unsigned short* __restrict__ mean) {
  int node = blockIdx.x * 4 + (threadIdx.x >> 6);
  int lane = threadIdx.x & 63;
  if (node >= N_NODES) return;
  int beg = rowp[node], end = rowp[node + 1];
  float a0 = 0.f, a1 = 0.f, a2 = 0.f, a3 = 0.f;
  int j = beg;
  for (; j + 2 <= end; j += 2) {
    int s0 = srcs[j], s1 = srcs[j + 1];
    uint2 u0 = *(const uint2*)(h + (size_t)s0 * DOUT + lane * 4);
    uint2 u1 = *(const uint2*)(h + (size_t)s1 * DOUT + lane * 4);
    a0 += bf2f(u0.x & 0xffff) + bf2f(u1.x & 0xffff);
    a1 += bf2f(u0.x >> 16)    + bf2f(u1.x >> 16);
    a2 += bf2f(u0.y & 0xffff) + bf2f(u1.y & 0xffff);
    a3 += bf2f(u0.y >> 16)    + bf2f(u1.y >> 16);
  }
  if (j < end) {
    int s0 = srcs[j];
    uint2 u0 = *(const uint2*)(h + (size_t)s0 * DOUT + lane * 4);
    a0 += bf2f(u0.x & 0xffff);
    a1 += bf2f(u0.x >> 16);
    a2 += bf2f(u0.y & 0xffff);
    a3 += bf2f(u0.y >> 16);
  }
  int d = deg[node];
  float inv = 1.0f / (float)(d > 1 ? d : 1);
  a0 *= inv; a1 *= inv; a2 *= inv; a3 *= inv;
  uint2 o;
  o.x = (unsigned)f2bf(a0) | ((unsigned)f2bf(a1) << 16);
  o.y = (unsigned)f2bf(a2) | ((unsigned)f2bf(a3) << 16);
  *(uint2*)(mean + (size_t)node * DOUT + lane * 4) = o;
}

// MFMA GEMM: C[m][n] = sum_k A[m][k]*BT[n][k] (+bias, relu?, +addend_f32?)
// A split at splitK between A0/A1 (conv: [mean | h]). a0f32: A0 is fp32 (x).
// BM=128 BN=64 BK=32; 4 waves, each 64x32 (4 m-frags x 2 n-frags).
__global__ __launch_bounds__(256) void gemm_sage(
    const void* __restrict__ A0p, const void* __restrict__ A1p,
    int lda0, int lda1, int splitK, int a0f32,
    const unsigned short* __restrict__ BT, const float* __restrict__ bias,
    const float* __restrict__ addend,
    float* __restrict__ outF, unsigned short* __restrict__ outB,
    int M, int K, int doRelu) {
  __shared__ unsigned short As[128 * 40];   // +8 pad per row
  __shared__ unsigned short Bs[64 * 40];

  const int tid  = threadIdx.x;
  const int lane = tid & 63;
  const int w    = tid >> 6;
  const int wm   = (w & 1) * 64;
  const int wn   = (w >> 1) * 32;
  const int bm   = blockIdx.x * 128;
  const int bn   = blockIdx.y * 64;

  f32x4 acc[4][2] = {};

  const int arow = tid >> 2;        // 0..63
  const int acol = (tid & 3) * 8;   // 0,8,16,24

  for (int kt = 0; kt < K; kt += 32) {
    __syncthreads();
    // stage A (128 rows, 2 passes)
    #pragma unroll
    for (int p = 0; p < 2; ++p) {
      int r  = p * 64 + arow;
      int gm = bm + r;
      int gk = kt + acol;
      uint4 val = make_uint4(0, 0, 0, 0);
      if (gm < M) {
        if (gk < splitK) {
          if (a0f32) {
            const float* ap = (const float*)A0p + (size_t)gm * lda0 + gk;
            float4 f0 = *(const float4*)ap;
            float4 f1 = *(const float4*)(ap + 4);
            val.x = (unsigned)f2bf(f0.x) | ((unsigned)f2bf(f0.y) << 16);
            val.y = (unsigned)f2bf(f0.z) | ((unsigned)f2bf(f0.w) << 16);
            val.z = (unsigned)f2bf(f1.x) | ((unsigned)f2bf(f1.y) << 16);
            val.w = (unsigned)f2bf(f1.z) | ((unsigned)f2bf(f1.w) << 16);
          } else {
            val = *(const uint4*)((const unsigned short*)A0p + (size_t)gm * lda0 + gk);
          }
        } else {
          val = *(const uint4*)((const unsigned short*)A1p + (size_t)gm * lda1 + (gk - splitK));
        }
      }
      *(uint4*)&As[r * 40 + acol] = val;
    }
    // stage B (64 n-rows of BT, k-contiguous)
    {
      int n  = arow;
      int gk = kt + acol;
      uint4 bv = *(const uint4*)(BT + (size_t)(bn + n) * K + gk);
      *(uint4*)&Bs[n * 40 + acol] = bv;
    }
    __syncthreads();

    const int k8   = (lane >> 4) * 8;
    const int mrow = lane & 15;
    short8 a[4], b[2];
    #pragma unroll
    for (int mi = 0; mi < 4; ++mi)
      a[mi] = *(const short8*)&As[(wm + mi * 16 + mrow) * 40 + k8];
    #pragma unroll
    for (int ni = 0; ni < 2; ++ni)
      b[ni] = *(const short8*)&Bs[(wn + ni * 16 + mrow) * 40 + k8];
    #pragma unroll
    for (int mi = 0; mi < 4; ++mi)
      #pragma unroll
      for (int ni = 0; ni < 2; ++ni)
        acc[mi][ni] = __builtin_amdgcn_mfma_f32_16x16x32_bf16(a[mi], b[ni], acc[mi][ni], 0, 0, 0);
  }

  // epilogue: C/D layout col=lane&15, row=(lane>>4)*4+reg  [m89-verified]
  const int cq   = lane >> 4;
  const int ccol = lane & 15;
  #pragma unroll
  for (int ni = 0; ni < 2; ++ni) {
    int gcol = bn + wn + ni * 16 + ccol;
    float bv = bias[gcol];
    #pragma unroll
    for (int mi = 0; mi < 4; ++mi) {
      #pragma unroll
      for (int r = 0; r < 4; ++r) {
        int grow = bm + wm + mi * 16 + cq * 4 + r;
        if (grow < M) {
          float v = acc[mi][ni][r] + bv;
          if (doRelu) v = fmaxf(v, 0.f);
          if (addend) v += addend[(size_t)grow * DOUT + gcol];
          if (outF) outF[(size_t)grow * DOUT + gcol] = v;
          if (outB) outB[(size_t)grow * DOUT + gcol] = f2bf(v);
        }
      }
    }
  }
}

extern "C" void kernel_launch(void* const* d_in, const int* in_sizes, int n_in,
                              void* d_out, int out_size, void* d_ws, size_t ws_size,
                              hipStream_t stream) {
  const float*    x   = (const float*)d_in[0];
  const unsigned* ei  = (const unsigned*)d_in[1];
  const float*    W0  = (const float*)d_in[2];
  const float*    b0  = (const float*)d_in[3];
  const float*    Wl1 = (const float*)d_in[4];
  const float*    bl1 = (const float*)d_in[5];
  const float*    Wr1 = (const float*)d_in[6];
  const float*    Wl2 = (const float*)d_in[7];
  const float*    bl2 = (const float*)d_in[8];
  const float*    Wr2 = (const float*)d_in[9];

  char* ws = (char*)d_ws;
  size_t off = 0;
  auto alloc = [&](size_t bytes) {
    char* p = ws + off;
    off += (bytes + 255) & ~(size_t)255;
    return p;
  };
  unsigned short* hb    = (unsigned short*)alloc((size_t)N_NODES * DOUT * 2);
  unsigned short* out1b = (unsigned short*)alloc((size_t)N_NODES * DOUT * 2);
  unsigned short* meanb = (unsigned short*)alloc((size_t)N_NODES * DOUT * 2);
  float*          hf    = (float*)alloc((size_t)N_NODES * DOUT * 4);
  unsigned short* W0T   = (unsigned short*)alloc(256 * 512 * 2);
  unsigned short* WT1   = (unsigned short*)alloc(256 * 512 * 2);
  unsigned short* WT2   = (unsigned short*)alloc(256 * 512 * 2);
  int* deg    = (int*)alloc(N_NODES * 4);
  int* rowp   = (int*)alloc((N_NODES + 1) * 4);
  int* cursor = (int*)alloc(N_NODES * 4);
  int* srcs   = (int*)alloc((size_t)N_EDGES * 4);
  int* flag   = (int*)alloc(256);

  float* out1 = (float*)d_out;
  float* out2 = out1 + (size_t)N_NODES * DOUT;

  hipMemsetAsync(deg, 0, N_NODES * 4, stream);
  detect_k<<<1, 64, 0, stream>>>(ei, flag);
  degree_k<<<(N_EDGES + 255) / 256, 256, 0, stream>>>(ei, flag, deg);
  scan_k<<<1, 1024, 0, stream>>>(deg, rowp, cursor);
  scatter_k<<<(N_EDGES + 255) / 256, 256, 0, stream>>>(ei, flag, cursor, srcs);
  prep_w<<<(3 * 256 * 512 + 255) / 256, 256, 0, stream>>>(W0, Wl1, Wr1, Wl2, Wr2, W0T, WT1, WT2);

  dim3 ggrid((N_NODES + 127) / 128, 4);
  // h = x @ W0 + b0   (writes hf fp32 + hb bf16)
  gemm_sage<<<ggrid, 256, 0, stream>>>(x, x, DIN, DIN, 512, 1,
                                       W0T, b0, nullptr, hf, hb, N_NODES, 512, 0);
  // mean1 = scatter-mean(h)
  agg_mean<<<(N_NODES + 3) / 4, 256, 0, stream>>>(hb, rowp, srcs, deg, meanb);
  // out1 = relu([mean1|h] @ [Wl1;Wr1] + bl1) + h
  gemm_sage<<<ggrid, 256, 0, stream>>>(meanb, hb, 256, 256, 256, 0,
                                       WT1, bl1, hf, out1, out1b, N_NODES, 512, 1);
  // mean2 = scatter-mean(out1)
  agg_mean<<<(N_NODES + 3) / 4, 256, 0, stream>>>(out1b, rowp, srcs, deg, meanb);
  // out2 = [mean2|out1] @ [Wl2;Wr2] + bl2 + out1
  gemm_sage<<<ggrid, 256, 0, stream>>>(meanb, out1b, 256, 256, 256, 0,
                                       WT2, bl2, out1, out2, nullptr, N_NODES, 512, 0);
}

// Round 2
// 237.318 us; speedup vs baseline: 1.2250x; 1.2250x over previous
//
#include <hip/hip_runtime.h>
#include <cstdint>

#define N_NODES 10000
#define N_EDGES 320000
#define DIN 512
#define DOUT 256
#define KDIM 512   // all GEMMs: K = 512 (gemm1: x@W0; conv: [mean|h]@[Wl;Wr])

using short8 = __attribute__((ext_vector_type(8))) short;
using f32x4  = __attribute__((ext_vector_type(4))) float;
typedef unsigned short ushort_t;

static __device__ __forceinline__ unsigned short f2bf(float f) {
  unsigned u = __builtin_bit_cast(unsigned, f);
  u += 0x7fffu + ((u >> 16) & 1u);   // round-to-nearest-even
  return (unsigned short)(u >> 16);
}
static __device__ __forceinline__ float bf2f(unsigned short s) {
  unsigned u = ((unsigned)s) << 16;
  return __builtin_bit_cast(float, u);
}

// Per-block int64-vs-int32 edge_index layout detection: for int64 data the odd
// u32 words are high halves == 0 (indices < 10000). For int32 data they are
// random indices; P(16 odd words all zero) ~ 0. Cheap: 16 L1-hit loads.
static __device__ __forceinline__ int detect64(const unsigned* ei) {
  unsigned z = 0;
  #pragma unroll
  for (int i = 1; i < 32; i += 2) z |= ei[i];
  return z == 0u;
}
static __device__ __forceinline__ int load_idx(const unsigned* ei, int i, int is64) {
  return is64 ? (int)ei[2 * i] : (int)ei[i];
}

// ---------------------------------------------------------------------------
// Fused setup: [0,1250) degree histogram; [1250,2786) weight transpose+bf16;
// [2786,7786) x fp32 -> bf16 cast. All block-uniform branches.
#define B_EDGE 1250
#define B_W    1536
#define B_X    5000
__global__ __launch_bounds__(256) void prep_all(
    const unsigned* __restrict__ ei, int* __restrict__ deg,
    const float* __restrict__ x, ushort_t* __restrict__ xb,
    const float* __restrict__ W0,
    const float* __restrict__ Wl1, const float* __restrict__ Wr1,
    const float* __restrict__ Wl2, const float* __restrict__ Wr2,
    ushort_t* __restrict__ W0T, ushort_t* __restrict__ WT1,
    ushort_t* __restrict__ WT2) {
  int b = blockIdx.x;
  if (b < B_EDGE) {
    int is64 = detect64(ei);
    int e = b * 256 + threadIdx.x;            // grid sized exactly: e < N_EDGES
    int d = load_idx(ei, N_EDGES + e, is64);
    atomicAdd(&deg[d], 1);
  } else if (b < B_EDGE + B_W) {
    int g = (b - B_EDGE) * 256 + threadIdx.x; // 0 .. 3*131072-1
    int mat = g >> 17;
    int r = g & 131071;
    int n = r >> 9, k = r & 511;
    float v;
    ushort_t* dst;
    if (mat == 0)      { v = W0[k * 256 + n]; dst = W0T; }
    else if (mat == 1) { v = (k < 256) ? Wl1[k * 256 + n] : Wr1[(k - 256) * 256 + n]; dst = WT1; }
    else               { v = (k < 256) ? Wl2[k * 256 + n] : Wr2[(k - 256) * 256 + n]; dst = WT2; }
    dst[r] = f2bf(v);
  } else {
    int g = (b - B_EDGE - B_W) * 256 + threadIdx.x;  // 0 .. 1,280,000-1
    float4 f = *(const float4*)(x + (size_t)g * 4);
    uint2 o;
    o.x = (unsigned)f2bf(f.x) | ((unsigned)f2bf(f.y) << 16);
    o.y = (unsigned)f2bf(f.z) | ((unsigned)f2bf(f.w) << 16);
    *(uint2*)(xb + (size_t)g * 4) = o;
  }
}

// single-block exclusive scan deg -> row_ptr (+ cursor copy)
__global__ __launch_bounds__(1024) void scan_k(const int* __restrict__ deg,
                                               int* __restrict__ rowp,
                                               int* __restrict__ cursor) {
  __shared__ int buf[1024];
  int tid = threadIdx.x;
  int loc[10];
  int s = 0;
  #pragma unroll
  for (int q = 0; q < 10; ++q) {
    int i = tid * 10 + q;
    int v = (i < N_NODES) ? deg[i] : 0;
    loc[q] = s;
    s += v;
  }
  buf[tid] = s;
  __syncthreads();
  #pragma unroll
  for (int off = 1; off < 1024; off <<= 1) {
    int t = (tid >= off) ? buf[tid - off] : 0;
    __syncthreads();
    buf[tid] += t;
    __syncthreads();
  }
  int excl = buf[tid] - s;
  #pragma unroll
  for (int q = 0; q < 10; ++q) {
    int i = tid * 10 + q;
    if (i < N_NODES) {
      int val = excl + loc[q];
      rowp[i] = val;
      cursor[i] = val;
    }
  }
  if (tid == 1023) rowp[N_NODES] = buf[1023];
}

__global__ __launch_bounds__(256) void scatter_k(const unsigned* __restrict__ ei,
                                                 int* __restrict__ cursor,
                                                 int* __restrict__ srcs) {
  int is64 = detect64(ei);
  int e = blockIdx.x * 256 + threadIdx.x;     // exact grid
  int d = load_idx(ei, N_EDGES + e, is64);
  int s = load_idx(ei, e, is64);
  int pos = atomicAdd(&cursor[d], 1);
  srcs[pos] = s;
}

// ---------------------------------------------------------------------------
// CSR mean-aggregate: one wave/node, lane = 4 cols, 4-edge unroll for MLP.
// h rows / mean rows live inside a [M x 512] combined buffer (stride 512).
__global__ __launch_bounds__(256) void agg_mean(const ushort_t* __restrict__ h,
                                                const int* __restrict__ rowp,
                                                const int* __restrict__ srcs,
                                                ushort_t* __restrict__ mean) {
  int node = blockIdx.x * 4 + (threadIdx.x >> 6);
  int lane = threadIdx.x & 63;
  if (node >= N_NODES) return;
  int beg = rowp[node], end = rowp[node + 1];
  float a0 = 0.f, a1 = 0.f, a2 = 0.f, a3 = 0.f;
  int j = beg;
  for (; j + 4 <= end; j += 4) {
    int s0 = srcs[j], s1 = srcs[j + 1], s2 = srcs[j + 2], s3 = srcs[j + 3];
    uint2 u0 = *(const uint2*)(h + (size_t)s0 * 512 + lane * 4);
    uint2 u1 = *(const uint2*)(h + (size_t)s1 * 512 + lane * 4);
    uint2 u2 = *(const uint2*)(h + (size_t)s2 * 512 + lane * 4);
    uint2 u3 = *(const uint2*)(h + (size_t)s3 * 512 + lane * 4);
    a0 += bf2f(u0.x & 0xffff) + bf2f(u1.x & 0xffff) + bf2f(u2.x & 0xffff) + bf2f(u3.x & 0xffff);
    a1 += bf2f(u0.x >> 16)    + bf2f(u1.x >> 16)    + bf2f(u2.x >> 16)    + bf2f(u3.x >> 16);
    a2 += bf2f(u0.y & 0xffff) + bf2f(u1.y & 0xffff) + bf2f(u2.y & 0xffff) + bf2f(u3.y & 0xffff);
    a3 += bf2f(u0.y >> 16)    + bf2f(u1.y >> 16)    + bf2f(u2.y >> 16)    + bf2f(u3.y >> 16);
  }
  for (; j < end; ++j) {
    int s0 = srcs[j];
    uint2 u0 = *(const uint2*)(h + (size_t)s0 * 512 + lane * 4);
    a0 += bf2f(u0.x & 0xffff);
    a1 += bf2f(u0.x >> 16);
    a2 += bf2f(u0.y & 0xffff);
    a3 += bf2f(u0.y >> 16);
  }
  int d = end - beg;
  float inv = 1.0f / (float)(d > 1 ? d : 1);
  a0 *= inv; a1 *= inv; a2 *= inv; a3 *= inv;
  uint2 o;
  o.x = (unsigned)f2bf(a0) | ((unsigned)f2bf(a1) << 16);
  o.y = (unsigned)f2bf(a2) | ((unsigned)f2bf(a3) << 16);
  *(uint2*)(mean + (size_t)node * 512 + lane * 4) = o;
}

// ---------------------------------------------------------------------------
// MFMA GEMM: C[M x 256] = A[M x 512](bf16) @ BT[256 x 512]^T (+bias, relu?,
// +fp32 addend?). BM=BN=64, BK=64 (8 K-iters, 16 MFMA/wave/iter-pair).
// 4 waves in 2x2, each computes 32x32 (acc[2][2] f32x4).
template<int DO_RELU, int HAS_ADD, int HAS_OUTB>
__global__ __launch_bounds__(256) void gemm_k(
    const ushort_t* __restrict__ A, const ushort_t* __restrict__ BT,
    const float* __restrict__ bias, const float* __restrict__ addend,
    float* __restrict__ outF, ushort_t* __restrict__ outB, int outB_ld, int M) {
  __shared__ ushort_t As[64 * 72];   // +8 shorts pad, keeps 16B align
  __shared__ ushort_t Bs[64 * 72];

  const int tid  = threadIdx.x;
  const int lane = tid & 63;
  const int w    = tid >> 6;
  const int wm   = (w & 1) * 32;
  const int wn   = (w >> 1) * 32;
  const int bm   = blockIdx.x * 64;
  const int bn   = blockIdx.y * 64;

  f32x4 acc[2][2] = {};

  const int srow = tid >> 3;        // 0..31
  const int scol = (tid & 7) * 8;   // 0..56 step 8

  for (int kt = 0; kt < KDIM; kt += 64) {
    __syncthreads();
    #pragma unroll
    for (int p = 0; p < 2; ++p) {
      int r = p * 32 + srow;
      int gm = bm + r;
      uint4 av = make_uint4(0, 0, 0, 0);
      if (gm < M) av = *(const uint4*)(A + (size_t)gm * KDIM + kt + scol);
      *(uint4*)&As[r * 72 + scol] = av;
      uint4 bv = *(const uint4*)(BT + (size_t)(bn + r) * KDIM + kt + scol);
      *(uint4*)&Bs[r * 72 + scol] = bv;
    }
    __syncthreads();

    const int mrow = lane & 15;
    const int k8   = (lane >> 4) * 8;
    #pragma unroll
    for (int s = 0; s < 2; ++s) {
      const int kc = s * 32 + k8;
      short8 a[2], b[2];
      #pragma unroll
      for (int mi = 0; mi < 2; ++mi)
        a[mi] = *(const short8*)&As[(wm + mi * 16 + mrow) * 72 + kc];
      #pragma unroll
      for (int ni = 0; ni < 2; ++ni)
        b[ni] = *(const short8*)&Bs[(wn + ni * 16 + mrow) * 72 + kc];
      #pragma unroll
      for (int mi = 0; mi < 2; ++mi)
        #pragma unroll
        for (int ni = 0; ni < 2; ++ni)
          acc[mi][ni] = __builtin_amdgcn_mfma_f32_16x16x32_bf16(a[mi], b[ni], acc[mi][ni], 0, 0, 0);
    }
  }

  // C/D layout: col = lane&15, row = (lane>>4)*4 + reg   [m89-verified]
  const int cq   = lane >> 4;
  const int ccol = lane & 15;
  #pragma unroll
  for (int ni = 0; ni < 2; ++ni) {
    int gcol = bn + wn + ni * 16 + ccol;
    float bv = bias[gcol];
    #pragma unroll
    for (int mi = 0; mi < 2; ++mi) {
      #pragma unroll
      for (int r = 0; r < 4; ++r) {
        int grow = bm + wm + mi * 16 + cq * 4 + r;
        if (grow < M) {
          float v = acc[mi][ni][r] + bv;
          if (DO_RELU) v = fmaxf(v, 0.f);
          if (HAS_ADD) v += addend[(size_t)grow * DOUT + gcol];
          outF[(size_t)grow * DOUT + gcol] = v;
          if (HAS_OUTB) outB[(size_t)grow * outB_ld + gcol] = f2bf(v);
        }
      }
    }
  }
}

// ---------------------------------------------------------------------------
extern "C" void kernel_launch(void* const* d_in, const int* in_sizes, int n_in,
                              void* d_out, int out_size, void* d_ws, size_t ws_size,
                              hipStream_t stream) {
  const float*    x   = (const float*)d_in[0];
  const unsigned* ei  = (const unsigned*)d_in[1];
  const float*    W0  = (const float*)d_in[2];
  const float*    b0  = (const float*)d_in[3];
  const float*    Wl1 = (const float*)d_in[4];
  const float*    bl1 = (const float*)d_in[5];
  const float*    Wr1 = (const float*)d_in[6];
  const float*    Wl2 = (const float*)d_in[7];
  const float*    bl2 = (const float*)d_in[8];
  const float*    Wr2 = (const float*)d_in[9];

  char* ws = (char*)d_ws;
  size_t off = 0;
  auto alloc = [&](size_t bytes) {
    char* p = ws + off;
    off += (bytes + 255) & ~(size_t)255;
    return p;
  };
  ushort_t* xb  = (ushort_t*)alloc((size_t)N_NODES * 512 * 2);  // x as bf16 [M x 512]
  ushort_t* c1  = (ushort_t*)alloc((size_t)N_NODES * 512 * 2);  // [mean1 | h]  rows
  ushort_t* c2  = (ushort_t*)alloc((size_t)N_NODES * 512 * 2);  // [mean2 | out1] rows
  float*    hf  = (float*)alloc((size_t)N_NODES * DOUT * 4);    // h fp32 (addend for gemm2)
  ushort_t* W0T = (ushort_t*)alloc(256 * 512 * 2);
  ushort_t* WT1 = (ushort_t*)alloc(256 * 512 * 2);
  ushort_t* WT2 = (ushort_t*)alloc(256 * 512 * 2);
  int* deg    = (int*)alloc(N_NODES * 4);
  int* rowp   = (int*)alloc((N_NODES + 1) * 4);
  int* cursor = (int*)alloc(N_NODES * 4);
  int* srcs   = (int*)alloc((size_t)N_EDGES * 4);

  float* out1 = (float*)d_out;
  float* out2 = out1 + (size_t)N_NODES * DOUT;

  hipMemsetAsync(deg, 0, N_NODES * 4, stream);
  prep_all<<<B_EDGE + B_W + B_X, 256, 0, stream>>>(ei, deg, x, xb,
                                                   W0, Wl1, Wr1, Wl2, Wr2,
                                                   W0T, WT1, WT2);
  scan_k<<<1, 1024, 0, stream>>>(deg, rowp, cursor);
  scatter_k<<<N_EDGES / 256, 256, 0, stream>>>(ei, cursor, srcs);

  dim3 ggrid((N_NODES + 63) / 64, 4);
  // h = x @ W0 + b0   -> hf (fp32), c1 right half (bf16)
  gemm_k<0, 0, 1><<<ggrid, 256, 0, stream>>>(xb, W0T, b0, nullptr,
                                             hf, c1 + 256, 512, N_NODES);
  // mean1 -> c1 left half
  agg_mean<<<(N_NODES + 3) / 4, 256, 0, stream>>>(c1 + 256, rowp, srcs, c1);
  // out1 = relu([mean1|h] @ [Wl1;Wr1] + bl1) + h  -> out1 (fp32), c2 right half
  gemm_k<1, 1, 1><<<ggrid, 256, 0, stream>>>(c1, WT1, bl1, hf,
                                             out1, c2 + 256, 512, N_NODES);
  // mean2 -> c2 left half
  agg_mean<<<(N_NODES + 3) / 4, 256, 0, stream>>>(c2 + 256, rowp, srcs, c2);
  // out2 = [mean2|out1] @ [Wl2;Wr2] + bl2 + out1
  gemm_k<0, 1, 0><<<ggrid, 256, 0, stream>>>(c2, WT2, bl2, out1,
                                             out2, nullptr, 0, N_NODES);
}

// Round 3
// 233.853 us; speedup vs baseline: 1.2432x; 1.0148x over previous
//
#include <hip/hip_runtime.h>
#include <cstdint>

#define N_NODES 10000
#define N_EDGES 320000
#define DIN 512
#define DOUT 256

using short8 = __attribute__((ext_vector_type(8))) short;
using f32x4  = __attribute__((ext_vector_type(4))) float;
typedef unsigned short ushort_t;

static __device__ __forceinline__ unsigned short f2bf(float f) {
  unsigned u = __builtin_bit_cast(unsigned, f);
  u += 0x7fffu + ((u >> 16) & 1u);   // round-to-nearest-even
  return (unsigned short)(u >> 16);
}
static __device__ __forceinline__ float bf2f(unsigned short s) {
  unsigned u = ((unsigned)s) << 16;
  return __builtin_bit_cast(float, u);
}

// int64-vs-int32 edge_index layout detect (odd u32 words all zero => int64).
static __device__ __forceinline__ int detect64(const unsigned* ei) {
  unsigned z = 0;
  #pragma unroll
  for (int i = 1; i < 32; i += 2) z |= ei[i];
  return z == 0u;
}
static __device__ __forceinline__ int load_idx(const unsigned* ei, int i, int is64) {
  return is64 ? (int)ei[2 * i] : (int)ei[i];
}

// ---------------------------------------------------------------------------
// Fused setup: [0,1250) degree histogram; [1250,2786) weight transpose+bf16;
// [2786,7786) x fp32 -> bf16 cast.
#define B_EDGE 1250
#define B_W    1536
#define B_X    5000
__global__ __launch_bounds__(256) void prep_all(
    const unsigned* __restrict__ ei, int* __restrict__ deg,
    const float* __restrict__ x, ushort_t* __restrict__ xb,
    const float* __restrict__ W0,
    const float* __restrict__ Wl1, const float* __restrict__ Wr1,
    const float* __restrict__ Wl2, const float* __restrict__ Wr2,
    ushort_t* __restrict__ W0T, ushort_t* __restrict__ WT1,
    ushort_t* __restrict__ WT2) {
  int b = blockIdx.x;
  if (b < B_EDGE) {
    int is64 = detect64(ei);
    int e = b * 256 + threadIdx.x;            // exact grid: e < N_EDGES
    int d = load_idx(ei, N_EDGES + e, is64);
    atomicAdd(&deg[d], 1);
  } else if (b < B_EDGE + B_W) {
    int g = (b - B_EDGE) * 256 + threadIdx.x; // 0 .. 3*131072-1
    int mat = g >> 17;
    int r = g & 131071;
    int n = r >> 9, k = r & 511;
    float v;
    ushort_t* dst;
    if (mat == 0)      { v = W0[k * 256 + n]; dst = W0T; }
    else if (mat == 1) { v = (k < 256) ? Wl1[k * 256 + n] : Wr1[(k - 256) * 256 + n]; dst = WT1; }
    else               { v = (k < 256) ? Wl2[k * 256 + n] : Wr2[(k - 256) * 256 + n]; dst = WT2; }
    dst[r] = f2bf(v);
  } else {
    int g = (b - B_EDGE - B_W) * 256 + threadIdx.x;  // 0 .. 1,280,000-1
    float4 f = *(const float4*)(x + (size_t)g * 4);
    uint2 o;
    o.x = (unsigned)f2bf(f.x) | ((unsigned)f2bf(f.y) << 16);
    o.y = (unsigned)f2bf(f.z) | ((unsigned)f2bf(f.w) << 16);
    *(uint2*)(xb + (size_t)g * 4) = o;
  }
}

// single-block exclusive scan deg -> row_ptr (+ cursor copy)
__global__ __launch_bounds__(1024) void scan_k(const int* __restrict__ deg,
                                               int* __restrict__ rowp,
                                               int* __restrict__ cursor) {
  __shared__ int buf[1024];
  int tid = threadIdx.x;
  int loc[10];
  int s = 0;
  #pragma unroll
  for (int q = 0; q < 10; ++q) {
    int i = tid * 10 + q;
    int v = (i < N_NODES) ? deg[i] : 0;
    loc[q] = s;
    s += v;
  }
  buf[tid] = s;
  __syncthreads();
  #pragma unroll
  for (int off = 1; off < 1024; off <<= 1) {
    int t = (tid >= off) ? buf[tid - off] : 0;
    __syncthreads();
    buf[tid] += t;
    __syncthreads();
  }
  int excl = buf[tid] - s;
  #pragma unroll
  for (int q = 0; q < 10; ++q) {
    int i = tid * 10 + q;
    if (i < N_NODES) {
      int val = excl + loc[q];
      rowp[i] = val;
      cursor[i] = val;
    }
  }
  if (tid == 1023) rowp[N_NODES] = buf[1023];
}

__global__ __launch_bounds__(256) void scatter_k(const unsigned* __restrict__ ei,
                                                 int* __restrict__ cursor,
                                                 int* __restrict__ srcs) {
  int is64 = detect64(ei);
  int e = blockIdx.x * 256 + threadIdx.x;     // exact grid
  int d = load_idx(ei, N_EDGES + e, is64);
  int s = load_idx(ei, e, is64);
  int pos = atomicAdd(&cursor[d], 1);
  srcs[pos] = s;
}

// ---------------------------------------------------------------------------
// CSR mean-aggregate: one wave/node, lane = 4 cols (uint2), 4-edge unroll.
// h: [M][256] bf16 compact (5 MB footprint ~ per-XCD L2).
__global__ __launch_bounds__(256) void agg_mean(const ushort_t* __restrict__ h,
                                                const int* __restrict__ rowp,
                                                const int* __restrict__ srcs,
                                                ushort_t* __restrict__ mean) {
  int node = blockIdx.x * 4 + (threadIdx.x >> 6);
  int lane = threadIdx.x & 63;
  if (node >= N_NODES) return;
  int beg = rowp[node], end = rowp[node + 1];
  float a0 = 0.f, a1 = 0.f, a2 = 0.f, a3 = 0.f;
  int j = beg;
  for (; j + 4 <= end; j += 4) {
    int s0 = srcs[j], s1 = srcs[j + 1], s2 = srcs[j + 2], s3 = srcs[j + 3];
    uint2 u0 = *(const uint2*)(h + (size_t)s0 * 256 + lane * 4);
    uint2 u1 = *(const uint2*)(h + (size_t)s1 * 256 + lane * 4);
    uint2 u2 = *(const uint2*)(h + (size_t)s2 * 256 + lane * 4);
    uint2 u3 = *(const uint2*)(h + (size_t)s3 * 256 + lane * 4);
    a0 += bf2f(u0.x & 0xffff) + bf2f(u1.x & 0xffff) + bf2f(u2.x & 0xffff) + bf2f(u3.x & 0xffff);
    a1 += bf2f(u0.x >> 16)    + bf2f(u1.x >> 16)    + bf2f(u2.x >> 16)    + bf2f(u3.x >> 16);
    a2 += bf2f(u0.y & 0xffff) + bf2f(u1.y & 0xffff) + bf2f(u2.y & 0xffff) + bf2f(u3.y & 0xffff);
    a3 += bf2f(u0.y >> 16)    + bf2f(u1.y >> 16)    + bf2f(u2.y >> 16)    + bf2f(u3.y >> 16);
  }
  for (; j < end; ++j) {
    int s0 = srcs[j];
    uint2 u0 = *(const uint2*)(h + (size_t)s0 * 256 + lane * 4);
    a0 += bf2f(u0.x & 0xffff);
    a1 += bf2f(u0.x >> 16);
    a2 += bf2f(u0.y & 0xffff);
    a3 += bf2f(u0.y >> 16);
  }
  int d = end - beg;
  float inv = 1.0f / (float)(d > 1 ? d : 1);
  a0 *= inv; a1 *= inv; a2 *= inv; a3 *= inv;
  uint2 o;
  o.x = (unsigned)f2bf(a0) | ((unsigned)f2bf(a1) << 16);
  o.y = (unsigned)f2bf(a2) | ((unsigned)f2bf(a3) << 16);
  *(uint2*)(mean + (size_t)node * 256 + lane * 4) = o;
}

// ---------------------------------------------------------------------------
// Panel-resident GEMM: C[M x 256] = A[M x 512] @ BT^T (+bias, relu?, +bf16
// addend?). Block owns a 64-col B panel (64x512 bf16 in LDS, loaded ONCE,
// row pad +8 -> 2-way-free banks) and 128 M-rows (4 waves x 32).
// Barrier-free K-loop: a-frags from global (one 16B load/lane), b-frags LDS.
// SPLIT_A: A = [A0 | A1] split at k=256 (both ld 256); else A0 with ld 512.
template<int DO_RELU, int HAS_ADD, int HAS_OUTF, int HAS_OUTB, int SPLIT_A>
__global__ __launch_bounds__(256) void gemm_pan(
    const ushort_t* __restrict__ A0, const ushort_t* __restrict__ A1,
    const ushort_t* __restrict__ BT, const float* __restrict__ bias,
    const ushort_t* __restrict__ addB,
    float* __restrict__ outF, ushort_t* __restrict__ outB, int M) {
  __shared__ ushort_t Bs[64 * 520];   // +8 pad

  const int tid  = threadIdx.x;
  const int lane = tid & 63;
  const int w    = tid >> 6;
  const int bn   = blockIdx.y * 64;
  const int mbase = blockIdx.x * 128 + w * 32;

  // stage B panel once: 64 rows x 512 k = 4096 uint4 chunks, 16 per thread
  #pragma unroll
  for (int i = 0; i < 16; ++i) {
    int c = i * 256 + tid;
    int row = c >> 6;
    int c8  = (c & 63) * 8;
    uint4 bv = *(const uint4*)(BT + (size_t)(bn + row) * 512 + c8);
    *(uint4*)&Bs[row * 520 + c8] = bv;
  }
  __syncthreads();

  f32x4 acc[2][4] = {};
  const int mrow = lane & 15;
  const int k8   = (lane >> 4) * 8;

  #pragma unroll
  for (int kt = 0; kt < 512; kt += 32) {
    const ushort_t* Asrc;
    int acol, ald;
    if (SPLIT_A) {
      if (kt < 256) { Asrc = A0; acol = kt; } else { Asrc = A1; acol = kt - 256; }
      ald = 256;
    } else {
      Asrc = A0; acol = kt; ald = 512;
    }
    short8 a[2], b[4];
    #pragma unroll
    for (int s = 0; s < 2; ++s) {
      int row = mbase + s * 16 + mrow;
      short8 av = {};
      if (row < M) av = *(const short8*)(Asrc + (size_t)row * ald + acol + k8);
      a[s] = av;
    }
    #pragma unroll
    for (int ni = 0; ni < 4; ++ni)
      b[ni] = *(const short8*)&Bs[(ni * 16 + mrow) * 520 + kt + k8];
    #pragma unroll
    for (int s = 0; s < 2; ++s)
      #pragma unroll
      for (int ni = 0; ni < 4; ++ni)
        acc[s][ni] = __builtin_amdgcn_mfma_f32_16x16x32_bf16(a[s], b[ni], acc[s][ni], 0, 0, 0);
  }

  // C/D layout: col = lane&15, row = (lane>>4)*4 + reg   [m89-verified]
  const int cq   = lane >> 4;
  const int ccol = lane & 15;
  #pragma unroll
  for (int ni = 0; ni < 4; ++ni) {
    int gcol = bn + ni * 16 + ccol;
    float bv = bias[gcol];
    #pragma unroll
    for (int s = 0; s < 2; ++s) {
      #pragma unroll
      for (int r = 0; r < 4; ++r) {
        int grow = mbase + s * 16 + cq * 4 + r;
        if (grow < M) {
          float v = acc[s][ni][r] + bv;
          if (DO_RELU) v = fmaxf(v, 0.f);
          if (HAS_ADD) v += bf2f(addB[(size_t)grow * DOUT + gcol]);
          if (HAS_OUTF) outF[(size_t)grow * DOUT + gcol] = v;
          if (HAS_OUTB) outB[(size_t)grow * DOUT + gcol] = f2bf(v);
        }
      }
    }
  }
}

// ---------------------------------------------------------------------------
extern "C" void kernel_launch(void* const* d_in, const int* in_sizes, int n_in,
                              void* d_out, int out_size, void* d_ws, size_t ws_size,
                              hipStream_t stream) {
  const float*    x   = (const float*)d_in[0];
  const unsigned* ei  = (const unsigned*)d_in[1];
  const float*    W0  = (const float*)d_in[2];
  const float*    b0  = (const float*)d_in[3];
  const float*    Wl1 = (const float*)d_in[4];
  const float*    bl1 = (const float*)d_in[5];
  const float*    Wr1 = (const float*)d_in[6];
  const float*    Wl2 = (const float*)d_in[7];
  const float*    bl2 = (const float*)d_in[8];
  const float*    Wr2 = (const float*)d_in[9];

  char* ws = (char*)d_ws;
  size_t off = 0;
  auto alloc = [&](size_t bytes) {
    char* p = ws + off;
    off += (bytes + 255) & ~(size_t)255;
    return p;
  };
  ushort_t* xb  = (ushort_t*)alloc((size_t)N_NODES * 512 * 2);  // x bf16 [M][512]
  ushort_t* hb  = (ushort_t*)alloc((size_t)N_NODES * 256 * 2);  // h bf16
  ushort_t* o1b = (ushort_t*)alloc((size_t)N_NODES * 256 * 2);  // out1 bf16
  ushort_t* mb  = (ushort_t*)alloc((size_t)N_NODES * 256 * 2);  // mean (reused)
  ushort_t* W0T = (ushort_t*)alloc(256 * 512 * 2);
  ushort_t* WT1 = (ushort_t*)alloc(256 * 512 * 2);
  ushort_t* WT2 = (ushort_t*)alloc(256 * 512 * 2);
  int* deg    = (int*)alloc(N_NODES * 4);
  int* rowp   = (int*)alloc((N_NODES + 1) * 4);
  int* cursor = (int*)alloc(N_NODES * 4);
  int* srcs   = (int*)alloc((size_t)N_EDGES * 4);

  float* out1 = (float*)d_out;
  float* out2 = out1 + (size_t)N_NODES * DOUT;

  hipMemsetAsync(deg, 0, N_NODES * 4, stream);
  prep_all<<<B_EDGE + B_W + B_X, 256, 0, stream>>>(ei, deg, x, xb,
                                                   W0, Wl1, Wr1, Wl2, Wr2,
                                                   W0T, WT1, WT2);
  scan_k<<<1, 1024, 0, stream>>>(deg, rowp, cursor);
  scatter_k<<<N_EDGES / 256, 256, 0, stream>>>(ei, cursor, srcs);

  dim3 ggrid((N_NODES + 127) / 128, 4);
  // h = x @ W0 + b0  (bf16 only; fp32 h not needed downstream)
  gemm_pan<0, 0, 0, 1, 0><<<ggrid, 256, 0, stream>>>(xb, nullptr, W0T, b0, nullptr,
                                                     nullptr, hb, N_NODES);
  // mean1 = scatter-mean(h)
  agg_mean<<<(N_NODES + 3) / 4, 256, 0, stream>>>(hb, rowp, srcs, mb);
  // out1 = relu([mean1|h] @ [Wl1;Wr1] + bl1) + h   (h addend in bf16)
  gemm_pan<1, 1, 1, 1, 1><<<ggrid, 256, 0, stream>>>(mb, hb, WT1, bl1, hb,
                                                     out1, o1b, N_NODES);
  // mean2 = scatter-mean(out1)
  agg_mean<<<(N_NODES + 3) / 4, 256, 0, stream>>>(o1b, rowp, srcs, mb);
  // out2 = [mean2|out1] @ [Wl2;Wr2] + bl2 + out1   (out1 addend in bf16)
  gemm_pan<0, 1, 1, 0, 1><<<ggrid, 256, 0, stream>>>(mb, o1b, WT2, bl2, o1b,
                                                     out2, nullptr, N_NODES);
}